// Round 1
// baseline (1377.308 us; speedup 1.0000x reference)
//
#include <hip/hip_runtime.h>
#include <hip/hip_bf16.h>
#include <cstdint>
#include <cstddef>

#define C_DIM   512
#define S_DIM   1024
#define N_BATCH 16
#define NHEADS  8
#define HDIM    64
#define NGROUPS 32

// ---------------------------------------------------------------------------
// Kernel 1: GroupNorm. One block per (n, group). Group = 16 ch x 1024 px,
// contiguous 16384 floats. Two stats (sum, sumsq) via shfl + LDS reduce.
// ---------------------------------------------------------------------------
__global__ __launch_bounds__(256) void gn_kernel(
    const float* __restrict__ x, const float* __restrict__ w,
    const float* __restrict__ b, float* __restrict__ h)
{
    const int n = blockIdx.x >> 5;
    const int g = blockIdx.x & 31;
    const size_t base = ((size_t)n * C_DIM + (size_t)g * 16) * S_DIM;
    const float4* xp = reinterpret_cast<const float4*>(x + base);

    float4 vals[16];
    float sum = 0.f, ss = 0.f;
#pragma unroll
    for (int i = 0; i < 16; ++i) {
        float4 v = xp[threadIdx.x + (i << 8)];
        vals[i] = v;
        sum += v.x + v.y + v.z + v.w;
        ss  += v.x*v.x + v.y*v.y + v.z*v.z + v.w*v.w;
    }
#pragma unroll
    for (int off = 32; off > 0; off >>= 1) {
        sum += __shfl_down(sum, off);
        ss  += __shfl_down(ss,  off);
    }
    __shared__ float rs[4], rq[4];
    const int wid = threadIdx.x >> 6, lane = threadIdx.x & 63;
    if (lane == 0) { rs[wid] = sum; rq[wid] = ss; }
    __syncthreads();
    const float tsum = rs[0] + rs[1] + rs[2] + rs[3];
    const float tss  = rq[0] + rq[1] + rq[2] + rq[3];
    const float mean = tsum * (1.0f / 16384.0f);
    const float var  = tss * (1.0f / 16384.0f) - mean * mean;
    const float inv  = rsqrtf(var + 1e-5f);

    float4* hp = reinterpret_cast<float4*>(h + base);
#pragma unroll
    for (int i = 0; i < 16; ++i) {
        // thread's i-th float4 lives entirely in channel (g*16 + i)
        const int c = g * 16 + i;
        const float A  = inv * w[c];
        const float Bc = b[c] - mean * A;
        float4 v = vals[i];
        v.x = v.x * A + Bc; v.y = v.y * A + Bc;
        v.z = v.z * A + Bc; v.w = v.w * A + Bc;
        hp[threadIdx.x + (i << 8)] = v;
    }
}

// ---------------------------------------------------------------------------
// Kernel 2/4: batched fp32 GEMM  out[n][m][s] = sum_k W[m][k]*Bm[n][k][s]
//             + bias[m] (+ resid). Tile 64x64, BK=16, 256 thr, 4x4 microtile.
// LDS padded to 68 floats/row: write-side 2-way max, read-side broadcast.
// ---------------------------------------------------------------------------
__global__ __launch_bounds__(256) void gemm_kernel(
    const float* __restrict__ W, const float* __restrict__ Bm,
    const float* __restrict__ bias, const float* __restrict__ resid,
    float* __restrict__ out, int M, int K)
{
    const int nb = blockIdx.z;
    const int m0 = blockIdx.y << 6;
    const int n0 = blockIdx.x << 6;
    const size_t bbase = (size_t)nb * K * S_DIM;
    const size_t obase = (size_t)nb * M * S_DIM;

    __shared__ float As[16][68];
    __shared__ float Bs[16][68];

    const int tx  = threadIdx.x & 15, ty = threadIdx.x >> 4;
    const int lm  = threadIdx.x >> 2;          // 0..63 (A row)
    const int lk4 = (threadIdx.x & 3) << 2;    // 0,4,8,12 (A k-chunk)
    const int lkb = threadIdx.x >> 4;          // 0..15 (B k row)
    const int ln4 = (threadIdx.x & 15) << 2;   // 0..60 (B col chunk)

    float acc[4][4];
#pragma unroll
    for (int i = 0; i < 4; ++i)
#pragma unroll
        for (int j = 0; j < 4; ++j) acc[i][j] = 0.f;

    const float* wp = W + (size_t)(m0 + lm) * K + lk4;
    const float* bp = Bm + bbase + (size_t)lkb * S_DIM + n0 + ln4;

    for (int k0 = 0; k0 < K; k0 += 16) {
        float4 av = *reinterpret_cast<const float4*>(wp + k0);
        float4 bv = *reinterpret_cast<const float4*>(bp + (size_t)k0 * S_DIM);
        As[lk4 + 0][lm] = av.x; As[lk4 + 1][lm] = av.y;
        As[lk4 + 2][lm] = av.z; As[lk4 + 3][lm] = av.w;
        *reinterpret_cast<float4*>(&Bs[lkb][ln4]) = bv;
        __syncthreads();
#pragma unroll
        for (int k = 0; k < 16; ++k) {
            float4 a  = *reinterpret_cast<const float4*>(&As[k][ty << 2]);
            float4 b4 = *reinterpret_cast<const float4*>(&Bs[k][tx << 2]);
            acc[0][0] += a.x*b4.x; acc[0][1] += a.x*b4.y; acc[0][2] += a.x*b4.z; acc[0][3] += a.x*b4.w;
            acc[1][0] += a.y*b4.x; acc[1][1] += a.y*b4.y; acc[1][2] += a.y*b4.z; acc[1][3] += a.y*b4.w;
            acc[2][0] += a.z*b4.x; acc[2][1] += a.z*b4.y; acc[2][2] += a.z*b4.z; acc[2][3] += a.z*b4.w;
            acc[3][0] += a.w*b4.x; acc[3][1] += a.w*b4.y; acc[3][2] += a.w*b4.z; acc[3][3] += a.w*b4.w;
        }
        __syncthreads();
    }

#pragma unroll
    for (int i = 0; i < 4; ++i) {
        const int row = m0 + (ty << 2) + i;
        const float bi = bias[row];
        const size_t o = obase + (size_t)row * S_DIM + n0 + (tx << 2);
        float4 v;
        v.x = acc[i][0] + bi; v.y = acc[i][1] + bi;
        v.z = acc[i][2] + bi; v.w = acc[i][3] + bi;
        if (resid) {
            float4 r = *reinterpret_cast<const float4*>(resid + o);
            v.x += r.x; v.y += r.y; v.z += r.z; v.w += r.w;
        }
        *reinterpret_cast<float4*>(out + o) = v;
    }
}

// ---------------------------------------------------------------------------
// Kernel 3: flash-style attention. One thread = one query. Q (scaled) and
// output accumulator live in registers (statically indexed). K/V tiles of 64
// keys staged TRANSPOSED in LDS ([t][d], pad 68) so the per-key dot/PV use
// float4 reads that are wave-uniform (same t) -> LDS broadcast, no conflict.
// Online softmax with rescale-only-on-new-max branch.
// ---------------------------------------------------------------------------
__global__ __launch_bounds__(256, 2) void attn_kernel(
    const float* __restrict__ qkv, float* __restrict__ out)
{
    const int qb = blockIdx.x;         // 0..3  (query block of 256)
    const int nh = blockIdx.y;         // 0..127 (n*8 + head)
    const int n  = nh >> 3, hh = nh & 7;
    const int q  = (qb << 8) + threadIdx.x;

    const size_t base = (size_t)n * 3 * C_DIM * S_DIM + (size_t)hh * HDIM * S_DIM;
    const float* Qp = qkv + base;
    const float* Kp = qkv + base + (size_t)C_DIM * S_DIM;
    const float* Vp = qkv + base + (size_t)2 * C_DIM * S_DIM;

    float qreg[64];
#pragma unroll
    for (int d = 0; d < 64; ++d)
        qreg[d] = Qp[(size_t)d * S_DIM + q] * 0.125f;  // fold 1/sqrt(64)

    float acc[64];
#pragma unroll
    for (int d = 0; d < 64; ++d) acc[d] = 0.f;
    float m = -INFINITY, l = 0.f;

    __shared__ float KtT[64][68];
    __shared__ float VtT[64][68];

    for (int t0 = 0; t0 < S_DIM; t0 += 64) {
        __syncthreads();
#pragma unroll
        for (int i = 0; i < 16; ++i) {
            const int idx = (i << 8) + threadIdx.x;
            const int d = idx >> 6, t = idx & 63;   // global read coalesced in t
            KtT[t][d] = Kp[(size_t)d * S_DIM + t0 + t];
            VtT[t][d] = Vp[(size_t)d * S_DIM + t0 + t];
        }
        __syncthreads();
#pragma unroll 1
        for (int t = 0; t < 64; ++t) {
            const float4* kt = reinterpret_cast<const float4*>(&KtT[t][0]);
            float s = 0.f;
#pragma unroll
            for (int d4 = 0; d4 < 16; ++d4) {
                float4 kv = kt[d4];
                s += qreg[4*d4+0]*kv.x + qreg[4*d4+1]*kv.y
                   + qreg[4*d4+2]*kv.z + qreg[4*d4+3]*kv.w;
            }
            const float4* vt = reinterpret_cast<const float4*>(&VtT[t][0]);
            if (s <= m) {
                const float p = __expf(s - m);
                l += p;
#pragma unroll
                for (int d4 = 0; d4 < 16; ++d4) {
                    float4 vv = vt[d4];
                    acc[4*d4+0] += p*vv.x; acc[4*d4+1] += p*vv.y;
                    acc[4*d4+2] += p*vv.z; acc[4*d4+3] += p*vv.w;
                }
            } else {
                const float al = __expf(m - s);   // exp(-inf)=0 handles first key
                l = l * al + 1.f;
                m = s;
#pragma unroll
                for (int d4 = 0; d4 < 16; ++d4) {
                    float4 vv = vt[d4];
                    acc[4*d4+0] = acc[4*d4+0]*al + vv.x;
                    acc[4*d4+1] = acc[4*d4+1]*al + vv.y;
                    acc[4*d4+2] = acc[4*d4+2]*al + vv.z;
                    acc[4*d4+3] = acc[4*d4+3]*al + vv.w;
                }
            }
        }
    }
    const float invl = 1.0f / l;
    const size_t ob = (size_t)n * C_DIM * S_DIM + (size_t)hh * HDIM * S_DIM + q;
#pragma unroll
    for (int d = 0; d < 64; ++d)
        out[ob + (size_t)d * S_DIM] = acc[d] * invl;   // coalesced per d
}

// ---------------------------------------------------------------------------
extern "C" void kernel_launch(void* const* d_in, const int* in_sizes, int n_in,
                              void* d_out, int out_size, void* d_ws, size_t ws_size,
                              hipStream_t stream)
{
    const float* x      = (const float*)d_in[0];
    const float* norm_w = (const float*)d_in[1];
    const float* norm_b = (const float*)d_in[2];
    const float* qkv_w  = (const float*)d_in[3];
    const float* qkv_b  = (const float*)d_in[4];
    const float* proj_w = (const float*)d_in[5];
    const float* proj_b = (const float*)d_in[6];
    float* out = (float*)d_out;

    // ws layout: h (32 MiB, later reused as attention output) | qkv (96 MiB)
    float* h   = (float*)d_ws;
    float* qkv = h + (size_t)N_BATCH * C_DIM * S_DIM;

    // 1) GroupNorm: x -> h
    hipLaunchKernelGGL(gn_kernel, dim3(N_BATCH * NGROUPS), dim3(256), 0, stream,
                       x, norm_w, norm_b, h);
    // 2) QKV 1x1 conv: h -> qkv   (M=1536, K=512)
    hipLaunchKernelGGL(gemm_kernel, dim3(S_DIM / 64, (3 * C_DIM) / 64, N_BATCH),
                       dim3(256), 0, stream,
                       qkv_w, h, qkv_b, (const float*)nullptr, qkv, 3 * C_DIM, C_DIM);
    // 3) attention: qkv -> h (reused as attn-out)
    hipLaunchKernelGGL(attn_kernel, dim3(S_DIM / 256, N_BATCH * NHEADS),
                       dim3(256), 0, stream, qkv, h);
    // 4) proj + bias + residual: h -> d_out  (M=512, K=512)
    hipLaunchKernelGGL(gemm_kernel, dim3(S_DIM / 64, C_DIM / 64, N_BATCH),
                       dim3(256), 0, stream,
                       proj_w, h, proj_b, x, out, C_DIM, C_DIM);
}

// Round 2
// 328.319 us; speedup vs baseline: 4.1950x; 4.1950x over previous
//
#include <hip/hip_runtime.h>
#include <cstdint>
#include <cstddef>

typedef unsigned short u16;
typedef __attribute__((ext_vector_type(8))) short bf16x8;   // 8 bf16 = 4 VGPR (guide §3)
typedef __attribute__((ext_vector_type(4))) float f32x4;
typedef __attribute__((ext_vector_type(4))) unsigned short u16x4;

#define NB 16
#define CD 512
#define SD 1024
#define NH 8
#define HD 64

__device__ __forceinline__ u16 f2bf(float f) {          // round-to-nearest-even
    unsigned u = __float_as_uint(f);
    u += 0x7FFF + ((u >> 16) & 1);
    return (u16)(u >> 16);
}
__device__ __forceinline__ void gload16(const void* g, void* l) {
    __builtin_amdgcn_global_load_lds(
        (const __attribute__((address_space(1))) void*)g,
        (__attribute__((address_space(3))) void*)l, 16, 0, 0);
}

// ---------------------------------------------------------------------------
// fp32 -> bf16 weight convert
// ---------------------------------------------------------------------------
__global__ __launch_bounds__(256) void cvt_kernel(
    const float* __restrict__ s, u16* __restrict__ d, int n)
{
    int i = (blockIdx.x * 256 + threadIdx.x) * 4;
    if (i >= n) return;
    float4 v = *reinterpret_cast<const float4*>(s + i);
    u16x4 o = { f2bf(v.x), f2bf(v.y), f2bf(v.z), f2bf(v.w) };
    *reinterpret_cast<u16x4*>(d + i) = o;
}

// ---------------------------------------------------------------------------
// GroupNorm: x [n][c][s] fp32 -> h [n][s][c] bf16 (transposed for GEMM B-op)
// ---------------------------------------------------------------------------
__global__ __launch_bounds__(256) void gn_kernel(
    const float* __restrict__ x, const float* __restrict__ w,
    const float* __restrict__ b, u16* __restrict__ h)
{
    const int n = blockIdx.x >> 5, g = blockIdx.x & 31;
    const size_t base = ((size_t)n * CD + g * 16) * SD;
    const float4* xp = reinterpret_cast<const float4*>(x + base);

    float4 vals[16];
    float sum = 0.f, ss = 0.f;
#pragma unroll
    for (int i = 0; i < 16; ++i) {
        float4 v = xp[threadIdx.x + (i << 8)];
        vals[i] = v;
        sum += v.x + v.y + v.z + v.w;
        ss  += v.x*v.x + v.y*v.y + v.z*v.z + v.w*v.w;
    }
#pragma unroll
    for (int off = 32; off > 0; off >>= 1) {
        sum += __shfl_down(sum, off);
        ss  += __shfl_down(ss,  off);
    }
    __shared__ float rs[4], rq[4];
    const int wid = threadIdx.x >> 6, lane = threadIdx.x & 63;
    if (lane == 0) { rs[wid] = sum; rq[wid] = ss; }
    __syncthreads();
    const float tsum = rs[0] + rs[1] + rs[2] + rs[3];
    const float tss  = rq[0] + rq[1] + rq[2] + rq[3];
    const float mean = tsum * (1.0f / 16384.0f);
    const float var  = tss * (1.0f / 16384.0f) - mean * mean;
    const float inv  = rsqrtf(var + 1e-5f);

    // thread covers pixels s = 4*tid..4*tid+3, channels g*16+i
    u16* hp = h + ((size_t)n * SD + 4 * threadIdx.x) * CD + g * 16;
#pragma unroll
    for (int i = 0; i < 16; ++i) {
        const float A  = inv * w[g * 16 + i];
        const float Bc = b[g * 16 + i] - mean * A;
        float4 v = vals[i];
        hp[i]          = f2bf(v.x * A + Bc);
        hp[CD + i]     = f2bf(v.y * A + Bc);
        hp[2 * CD + i] = f2bf(v.z * A + Bc);
        hp[3 * CD + i] = f2bf(v.w * A + Bc);
    }
}

// ---------------------------------------------------------------------------
// MFMA GEMM: D[m][s] = sum_k W[m][k] * act[n][s][k], K = 512 fixed.
// Tile 128x128, BK=64, 4 waves (2x2), 16x16x32 bf16 MFMA, 4x4 frags/wave.
// Both LDS tiles staged via global_load_lds with XOR-granule source swizzle:
// LDS[row][g] holds global granule (g ^ (row&7)) -> frag b128 reads 2-way free.
// mode 0: out bf16 [n][s][M] + bias.   mode 1: out fp32 [n][M][s] + bias + resid.
// ---------------------------------------------------------------------------
__global__ __launch_bounds__(256) void mfma_gemm(
    const u16* __restrict__ Wb, const u16* __restrict__ act,
    const float* __restrict__ bias, const float* __restrict__ resid,
    void* __restrict__ outp, int M, int mode)
{
    const int nb = blockIdx.z, m0 = blockIdx.y * 128, s0 = blockIdx.x * 128;
    __shared__ u16 Al[128 * 64];
    __shared__ u16 Bl[128 * 64];
    const int tid = threadIdx.x, wv = tid >> 6, ln = tid & 63;
    const int wm = wv >> 1, wn = wv & 1, lr = ln & 15, lg = ln >> 4;

    const f32x4 zero = {0.f, 0.f, 0.f, 0.f};
    f32x4 acc[4][4];
#pragma unroll
    for (int i = 0; i < 4; ++i)
#pragma unroll
        for (int j = 0; j < 4; ++j) acc[i][j] = zero;

    const u16* Ab = Wb + (size_t)m0 * CD;
    const u16* Bb = act + ((size_t)nb * SD + s0) * CD;

    for (int k0 = 0; k0 < CD; k0 += 64) {
        __syncthreads();
#pragma unroll
        for (int r = 0; r < 4; ++r) {
            const int gi = (r * 4 + wv) * 64 + ln;        // lane-contiguous dest
            const int row = gi >> 3, gc = gi & 7;
            const int sg = ((gc ^ (row & 7)) * 8);
            gload16(Ab + (size_t)row * CD + k0 + sg, Al + gi * 8);
            gload16(Bb + (size_t)row * CD + k0 + sg, Bl + gi * 8);
        }
        __syncthreads();

        bf16x8 af[4][2], bfr[4][2];
#pragma unroll
        for (int mi = 0; mi < 4; ++mi) {
            const int row = wm * 64 + mi * 16 + lr;
#pragma unroll
            for (int kc = 0; kc < 2; ++kc)
                af[mi][kc] = *reinterpret_cast<const bf16x8*>(
                    Al + row * 64 + (((kc * 4 + lg) ^ (row & 7)) * 8));
        }
#pragma unroll
        for (int nj = 0; nj < 4; ++nj) {
            const int row = wn * 64 + nj * 16 + lr;
#pragma unroll
            for (int kc = 0; kc < 2; ++kc)
                bfr[nj][kc] = *reinterpret_cast<const bf16x8*>(
                    Bl + row * 64 + (((kc * 4 + lg) ^ (row & 7)) * 8));
        }
#pragma unroll
        for (int kc = 0; kc < 2; ++kc)
#pragma unroll
            for (int mi = 0; mi < 4; ++mi)
#pragma unroll
                for (int nj = 0; nj < 4; ++nj)
                    acc[mi][nj] = __builtin_amdgcn_mfma_f32_16x16x32_bf16(
                        af[mi][kc], bfr[nj][kc], acc[mi][nj], 0, 0, 0);
    }

    if (mode == 0) {
        u16* o = (u16*)outp;
#pragma unroll
        for (int mi = 0; mi < 4; ++mi)
#pragma unroll
            for (int r = 0; r < 4; ++r) {
                const int m = m0 + wm * 64 + mi * 16 + lg * 4 + r;
                const float bi = bias[m];
#pragma unroll
                for (int nj = 0; nj < 4; ++nj) {
                    const int s = s0 + wn * 64 + nj * 16 + lr;
                    o[((size_t)nb * SD + s) * M + m] = f2bf(acc[mi][nj][r] + bi);
                }
            }
    } else {
        float* o = (float*)outp;
#pragma unroll
        for (int mi = 0; mi < 4; ++mi)
#pragma unroll
            for (int r = 0; r < 4; ++r) {
                const int m = m0 + wm * 64 + mi * 16 + lg * 4 + r;
                const float bi = bias[m];
#pragma unroll
                for (int nj = 0; nj < 4; ++nj) {
                    const int s = s0 + wn * 64 + nj * 16 + lr;
                    const size_t idx = ((size_t)nb * M + m) * SD + s;
                    o[idx] = acc[mi][nj][r] + bi + resid[idx];
                }
            }
    }
}

// ---------------------------------------------------------------------------
// Flash attention, bf16 MFMA. Block = one (n,head) x 64-query tile, 4 waves
// (16 q-rows each). KVBLK=64. qkv layout [n][s][1536] (q|k|v per pixel).
//   S[q][t] = sum_d Q^T[q][d] K[d][t]:  A = Q^T (regs), B = K (LDS, swizzled)
//   O[q][d] += P[q][t] V[t][d]:         A = P (per-wave LDS), B = V^T (LDS)
// Online softmax per q-row in registers (shfl reduce over 16 t-cols).
// ---------------------------------------------------------------------------
__global__ __launch_bounds__(256) void attn_mfma(
    const u16* __restrict__ qkv, u16* __restrict__ ao)
{
    const int nh = blockIdx.y, n = nh >> 3, hh = nh & 7;
    const int q0 = blockIdx.x * 64;
    const int tid = threadIdx.x, wv = tid >> 6, ln = tid & 63;
    const int lr = ln & 15, lg = ln >> 4;

    __shared__ u16 Kl[64 * 64];        // [t][d], XOR-swizzled granules
    __shared__ u16 Vt[64 * 72];        // [d][t], pad->144B rows (16B aligned)
    __shared__ u16 Pl[4][16 * 72];     // per-wave P [q][t]

    const u16* base = qkv + (size_t)n * SD * 1536 + hh * HD;
    const u16* Qb = base;
    const u16* Kb = base + 512;
    const u16* Vb = base + 1024;

    bf16x8 qf[2];
    {
        const u16* qp = Qb + (size_t)(q0 + wv * 16 + lr) * 1536;
        qf[0] = *reinterpret_cast<const bf16x8*>(qp + lg * 8);
        qf[1] = *reinterpret_cast<const bf16x8*>(qp + 32 + lg * 8);
    }
    const f32x4 zero = {0.f, 0.f, 0.f, 0.f};
    f32x4 of[4];
#pragma unroll
    for (int i = 0; i < 4; ++i) of[i] = zero;
    float mrow[4] = {-INFINITY, -INFINITY, -INFINITY, -INFINITY};
    float lrow[4] = {0.f, 0.f, 0.f, 0.f};

    for (int t0 = 0; t0 < SD; t0 += 64) {
        __syncthreads();
        // stage K tile via global_load_lds, source-swizzled granules
#pragma unroll
        for (int r2 = 0; r2 < 2; ++r2) {
            const int gi = (r2 * 4 + wv) * 64 + ln;
            const int row = gi >> 3, gc = gi & 7;
            const int sg = ((gc ^ (row & 7)) * 8);
            gload16(Kb + (size_t)(t0 + row) * 1536 + sg, Kl + gi * 8);
        }
        // stage V transposed via regs (coalesced 16B reads, 2-way-free writes)
        {
            const int tr = tid >> 2, db = (tid & 3) * 16;
            const u16* vp = Vb + (size_t)(t0 + tr) * 1536 + db;
            bf16x8 v0 = *reinterpret_cast<const bf16x8*>(vp);
            bf16x8 v1 = *reinterpret_cast<const bf16x8*>(vp + 8);
#pragma unroll
            for (int j = 0; j < 8; ++j) {
                Vt[(db + j) * 72 + tr]     = (u16)v0[j];
                Vt[(db + 8 + j) * 72 + tr] = (u16)v1[j];
            }
        }
        __syncthreads();

        // QK^T: 8 MFMA -> S[q][t] frags (row=q=lg*4+r, col=t=lr)
        f32x4 st[4];
#pragma unroll
        for (int tt = 0; tt < 4; ++tt) st[tt] = zero;
#pragma unroll
        for (int tt = 0; tt < 4; ++tt) {
            const int trow = tt * 16 + lr;
#pragma unroll
            for (int kc = 0; kc < 2; ++kc) {
                bf16x8 kf = *reinterpret_cast<const bf16x8*>(
                    Kl + trow * 64 + (((kc * 4 + lg) ^ (trow & 7)) * 8));
                st[tt] = __builtin_amdgcn_mfma_f32_16x16x32_bf16(qf[kc], kf, st[tt], 0, 0, 0);
            }
        }
        // online softmax (scale 1/8 folded into exp arg; branchless rescale)
        float al[4];
#pragma unroll
        for (int r = 0; r < 4; ++r) {
            float mx = fmaxf(fmaxf(st[0][r], st[1][r]), fmaxf(st[2][r], st[3][r])) * 0.125f;
#pragma unroll
            for (int off = 1; off < 16; off <<= 1) mx = fmaxf(mx, __shfl_xor(mx, off));
            const float mn = fmaxf(mrow[r], mx);
            al[r] = __expf(mrow[r] - mn);          // exp(-inf)=0 on first tile
            mrow[r] = mn;
            float ps = 0.f;
#pragma unroll
            for (int tt = 0; tt < 4; ++tt) {
                const float p = __expf(st[tt][r] * 0.125f - mn);
                st[tt][r] = p; ps += p;
            }
#pragma unroll
            for (int off = 1; off < 16; off <<= 1) ps += __shfl_xor(ps, off);
            lrow[r] = lrow[r] * al[r] + ps;
        }
#pragma unroll
        for (int dt = 0; dt < 4; ++dt)
#pragma unroll
            for (int r = 0; r < 4; ++r) of[dt][r] *= al[r];

        // P -> per-wave LDS (bf16), conflict-free scalar writes
        u16* pw = &Pl[wv][0];
#pragma unroll
        for (int tt = 0; tt < 4; ++tt)
#pragma unroll
            for (int r = 0; r < 4; ++r)
                pw[(lg * 4 + r) * 72 + tt * 16 + lr] = f2bf(st[tt][r]);

        // PV: 8 MFMA
#pragma unroll
        for (int kc = 0; kc < 2; ++kc) {
            bf16x8 pf = *reinterpret_cast<const bf16x8*>(pw + lr * 72 + kc * 32 + lg * 8);
#pragma unroll
            for (int dt = 0; dt < 4; ++dt) {
                bf16x8 vf = *reinterpret_cast<const bf16x8*>(
                    Vt + (dt * 16 + lr) * 72 + kc * 32 + lg * 8);
                of[dt] = __builtin_amdgcn_mfma_f32_16x16x32_bf16(pf, vf, of[dt], 0, 0, 0);
            }
        }
    }

    float inv[4];
#pragma unroll
    for (int r = 0; r < 4; ++r) inv[r] = 1.0f / lrow[r];
    const int q = q0 + wv * 16 + lg * 4;
#pragma unroll
    for (int r = 0; r < 4; ++r) {
        u16* op = ao + ((size_t)n * SD + q + r) * CD + hh * HD + lr;
#pragma unroll
        for (int dt = 0; dt < 4; ++dt)
            op[dt * 16] = f2bf(of[dt][r] * inv[r]);
    }
}

// ---------------------------------------------------------------------------
extern "C" void kernel_launch(void* const* d_in, const int* in_sizes, int n_in,
                              void* d_out, int out_size, void* d_ws, size_t ws_size,
                              hipStream_t stream)
{
    const float* x      = (const float*)d_in[0];
    const float* norm_w = (const float*)d_in[1];
    const float* norm_b = (const float*)d_in[2];
    const float* qkv_w  = (const float*)d_in[3];
    const float* qkv_b  = (const float*)d_in[4];
    const float* proj_w = (const float*)d_in[5];
    const float* proj_b = (const float*)d_in[6];

    // ws: h | qkv | attn-out | wq_bf16 | wp_bf16  (~86 MiB total)
    u16* h   = (u16*)d_ws;                      // [16][1024][512]
    u16* qkv = h + (size_t)NB * SD * CD;        // [16][1024][1536]
    u16* ao  = qkv + (size_t)NB * SD * 1536;    // [16][1024][512]
    u16* wq  = ao + (size_t)NB * SD * CD;       // [1536][512]
    u16* wp  = wq + (size_t)1536 * CD;          // [512][512]

    hipLaunchKernelGGL(cvt_kernel, dim3(768), dim3(256), 0, stream, qkv_w, wq, 1536 * CD);
    hipLaunchKernelGGL(cvt_kernel, dim3(256), dim3(256), 0, stream, proj_w, wp, CD * CD);
    hipLaunchKernelGGL(gn_kernel, dim3(NB * 32), dim3(256), 0, stream, x, norm_w, norm_b, h);
    hipLaunchKernelGGL(mfma_gemm, dim3(8, 12, NB), dim3(256), 0, stream,
                       wq, h, qkv_b, (const float*)nullptr, (void*)qkv, 1536, 0);
    hipLaunchKernelGGL(attn_mfma, dim3(16, 128), dim3(256), 0, stream, qkv, ao);
    hipLaunchKernelGGL(mfma_gemm, dim3(8, 4, NB), dim3(256), 0, stream,
                       wp, ao, proj_b, x, (void*)d_out, 512, 1);
}

// Round 3
// 225.004 us; speedup vs baseline: 6.1213x; 1.4592x over previous
//
#include <hip/hip_runtime.h>
#include <cstdint>
#include <cstddef>

typedef unsigned short u16;
typedef __attribute__((ext_vector_type(8))) short bf16x8;   // 8 bf16 = 4 VGPR
typedef __attribute__((ext_vector_type(4))) short bf16x4;   // 4 bf16 = 2 VGPR
typedef __attribute__((ext_vector_type(4))) float f32x4;
typedef __attribute__((ext_vector_type(16))) float f32x16;
typedef __attribute__((ext_vector_type(4))) unsigned short u16x4;

#define NB 16
#define CD 512
#define SD 1024
#define NH 8
#define HD 64

__device__ __forceinline__ u16 f2bf(float f) {          // round-to-nearest-even
    unsigned u = __float_as_uint(f);
    u += 0x7FFF + ((u >> 16) & 1);
    return (u16)(u >> 16);
}
__device__ __forceinline__ unsigned cvt_pk(float lo, float hi) {
    unsigned r;
    asm("v_cvt_pk_bf16_f32 %0, %1, %2" : "=v"(r) : "v"(lo), "v"(hi));
    return r;
}
__device__ __forceinline__ void gload16(const void* g, void* l) {
    __builtin_amdgcn_global_load_lds(
        (const __attribute__((address_space(1))) void*)g,
        (__attribute__((address_space(3))) void*)l, 16, 0, 0);
}

// ---------------------------------------------------------------------------
// fp32 -> bf16 weight convert
// ---------------------------------------------------------------------------
__global__ __launch_bounds__(256) void cvt_kernel(
    const float* __restrict__ s, u16* __restrict__ d, int n)
{
    int i = (blockIdx.x * 256 + threadIdx.x) * 4;
    if (i >= n) return;
    float4 v = *reinterpret_cast<const float4*>(s + i);
    u16x4 o = { f2bf(v.x), f2bf(v.y), f2bf(v.z), f2bf(v.w) };
    *reinterpret_cast<u16x4*>(d + i) = o;
}

// ---------------------------------------------------------------------------
// GroupNorm: x [n][c][s] fp32 -> h [n][s][c] bf16
// ---------------------------------------------------------------------------
__global__ __launch_bounds__(256) void gn_kernel(
    const float* __restrict__ x, const float* __restrict__ w,
    const float* __restrict__ b, u16* __restrict__ h)
{
    const int n = blockIdx.x >> 5, g = blockIdx.x & 31;
    const size_t base = ((size_t)n * CD + g * 16) * SD;
    const float4* xp = reinterpret_cast<const float4*>(x + base);

    float4 vals[16];
    float sum = 0.f, ss = 0.f;
#pragma unroll
    for (int i = 0; i < 16; ++i) {
        float4 v = xp[threadIdx.x + (i << 8)];
        vals[i] = v;
        sum += v.x + v.y + v.z + v.w;
        ss  += v.x*v.x + v.y*v.y + v.z*v.z + v.w*v.w;
    }
#pragma unroll
    for (int off = 32; off > 0; off >>= 1) {
        sum += __shfl_down(sum, off);
        ss  += __shfl_down(ss,  off);
    }
    __shared__ float rs[4], rq[4];
    const int wid = threadIdx.x >> 6, lane = threadIdx.x & 63;
    if (lane == 0) { rs[wid] = sum; rq[wid] = ss; }
    __syncthreads();
    const float tsum = rs[0] + rs[1] + rs[2] + rs[3];
    const float tss  = rq[0] + rq[1] + rq[2] + rq[3];
    const float mean = tsum * (1.0f / 16384.0f);
    const float var  = tss * (1.0f / 16384.0f) - mean * mean;
    const float inv  = rsqrtf(var + 1e-5f);

    u16* hp = h + ((size_t)n * SD + 4 * threadIdx.x) * CD + g * 16;
#pragma unroll
    for (int i = 0; i < 16; ++i) {
        const float A  = inv * w[g * 16 + i];
        const float Bc = b[g * 16 + i] - mean * A;
        float4 v = vals[i];
        hp[i]          = f2bf(v.x * A + Bc);
        hp[CD + i]     = f2bf(v.y * A + Bc);
        hp[2 * CD + i] = f2bf(v.z * A + Bc);
        hp[3 * CD + i] = f2bf(v.w * A + Bc);
    }
}

// ---------------------------------------------------------------------------
// MFMA GEMM: D[m][s] = sum_k W[m][k] * act[n][s][k], K = 512.
// Tile 128x128, BK=64, 4 waves, 16x16x32 MFMA, XOR-granule swizzled LDS.
// mode 0: m<1024 -> qk [n][s][1024] bf16 + bias;  m>=1024 -> vt [n*512+m-1024][s]
// mode 1: out fp32 [n][M][s] + bias + resid.
// ---------------------------------------------------------------------------
__global__ __launch_bounds__(256) void mfma_gemm(
    const u16* __restrict__ Wb, const u16* __restrict__ act,
    const float* __restrict__ bias, const float* __restrict__ resid,
    void* __restrict__ outp, u16* __restrict__ vtout, int M, int mode)
{
    const int nb = blockIdx.z, m0 = blockIdx.y * 128, s0 = blockIdx.x * 128;
    __shared__ u16 Al[128 * 64];
    __shared__ u16 Bl[128 * 64];
    const int tid = threadIdx.x, wv = tid >> 6, ln = tid & 63;
    const int wm = wv >> 1, wn = wv & 1, lr = ln & 15, lg = ln >> 4;

    const f32x4 zero = {0.f, 0.f, 0.f, 0.f};
    f32x4 acc[4][4];
#pragma unroll
    for (int i = 0; i < 4; ++i)
#pragma unroll
        for (int j = 0; j < 4; ++j) acc[i][j] = zero;

    const u16* Ab = Wb + (size_t)m0 * CD;
    const u16* Bb = act + ((size_t)nb * SD + s0) * CD;

    for (int k0 = 0; k0 < CD; k0 += 64) {
        __syncthreads();
#pragma unroll
        for (int r = 0; r < 4; ++r) {
            const int gi = (r * 4 + wv) * 64 + ln;
            const int row = gi >> 3, gc = gi & 7;
            const int sg = ((gc ^ (row & 7)) * 8);
            gload16(Ab + (size_t)row * CD + k0 + sg, Al + gi * 8);
            gload16(Bb + (size_t)row * CD + k0 + sg, Bl + gi * 8);
        }
        __syncthreads();

        bf16x8 af[4][2], bfr[4][2];
#pragma unroll
        for (int mi = 0; mi < 4; ++mi) {
            const int row = wm * 64 + mi * 16 + lr;
#pragma unroll
            for (int kc = 0; kc < 2; ++kc)
                af[mi][kc] = *reinterpret_cast<const bf16x8*>(
                    Al + row * 64 + (((kc * 4 + lg) ^ (row & 7)) * 8));
        }
#pragma unroll
        for (int nj = 0; nj < 4; ++nj) {
            const int row = wn * 64 + nj * 16 + lr;
#pragma unroll
            for (int kc = 0; kc < 2; ++kc)
                bfr[nj][kc] = *reinterpret_cast<const bf16x8*>(
                    Bl + row * 64 + (((kc * 4 + lg) ^ (row & 7)) * 8));
        }
#pragma unroll
        for (int kc = 0; kc < 2; ++kc)
#pragma unroll
            for (int mi = 0; mi < 4; ++mi)
#pragma unroll
                for (int nj = 0; nj < 4; ++nj)
                    acc[mi][nj] = __builtin_amdgcn_mfma_f32_16x16x32_bf16(
                        af[mi][kc], bfr[nj][kc], acc[mi][nj], 0, 0, 0);
    }

    if (mode == 0) {
        if (m0 < 1024) {                                     // Q|K -> qk[n][s][1024]
            u16* o = (u16*)outp;
#pragma unroll
            for (int mi = 0; mi < 4; ++mi)
#pragma unroll
                for (int r = 0; r < 4; ++r) {
                    const int m = m0 + wm * 64 + mi * 16 + lg * 4 + r;
                    const float bi = bias[m];
#pragma unroll
                    for (int nj = 0; nj < 4; ++nj) {
                        const int s = s0 + wn * 64 + nj * 16 + lr;
                        o[((size_t)nb * SD + s) * 1024 + m] = f2bf(acc[mi][nj][r] + bi);
                    }
                }
        } else {                                             // V -> vt[(n*512+c)][s]
#pragma unroll
            for (int mi = 0; mi < 4; ++mi)
#pragma unroll
                for (int r = 0; r < 4; ++r) {
                    const int m = m0 + wm * 64 + mi * 16 + lg * 4 + r;
                    const float bi = bias[m];
#pragma unroll
                    for (int nj = 0; nj < 4; ++nj) {
                        const int s = s0 + wn * 64 + nj * 16 + lr;
                        vtout[((size_t)nb * 512 + (m - 1024)) * SD + s] = f2bf(acc[mi][nj][r] + bi);
                    }
                }
        }
    } else {
        float* o = (float*)outp;
#pragma unroll
        for (int mi = 0; mi < 4; ++mi)
#pragma unroll
            for (int r = 0; r < 4; ++r) {
                const int m = m0 + wm * 64 + mi * 16 + lg * 4 + r;
                const float bi = bias[m];
#pragma unroll
                for (int nj = 0; nj < 4; ++nj) {
                    const int s = s0 + wn * 64 + nj * 16 + lr;
                    const size_t idx = ((size_t)nb * M + m) * SD + s;
                    o[idx] = acc[mi][nj][r] + bi + resid[idx];
                }
            }
    }
}

// ---------------------------------------------------------------------------
// Flash attention, 32x32x16 bf16 MFMA, swapped QK^T (S^T = K·Q^T) so the
// softmax state (m,l) is one scalar per lane (q = lane&31) and P never leaves
// registers. 8 waves x 32 q-rows = 256 q/block; KV tiles of 64, double-
// buffered K [t][64] and V^T [d][64t] in LDS via gload16 + XOR-granule source
// swizzle (bank-floor-optimal frag reads). PV consumes V^T with 2 x b64 reads
// in t-order {4hi+0..3, 8+4hi+0..3} == the S^T C-frag's native per-lane order,
// so P-frags need only 4 cvt_pk each (no shuffles, no LDS round-trip).
// O^T = V^T · P^T keeps normalization lane-local too.
// ---------------------------------------------------------------------------
__global__ __launch_bounds__(512) void attn_mfma(
    const u16* __restrict__ qk, const u16* __restrict__ vt, u16* __restrict__ ao)
{
    const int nh = blockIdx.y, n = nh >> 3, hh = nh & 7;
    const int q0 = blockIdx.x << 8;
    const int tid = threadIdx.x, wv = tid >> 6, ln = tid & 63;
    const int lq = ln & 31, hi = ln >> 5;

    __shared__ u16 Kl[2][64 * 64];     // [t][d] granule-swizzled
    __shared__ u16 Vl[2][64 * 64];     // [d][t] granule-swizzled

    const u16* Qb = qk + (size_t)n * SD * 1024 + hh * HD;
    const u16* Kb = Qb + 512;
    const u16* Vb = vt + ((size_t)n * 512 + hh * HD) * SD;

    // Q B-frags: lane: q = q0+wv*32+lq, d = ks*16 + hi*8 + j
    bf16x8 qf[4];
    {
        const u16* qp = Qb + (size_t)(q0 + wv * 32 + lq) * 1024 + hi * 8;
#pragma unroll
        for (int ks = 0; ks < 4; ++ks)
            qf[ks] = *reinterpret_cast<const bf16x8*>(qp + ks * 16);
    }

    f32x16 of0 = {}, of1 = {};         // O^T frags: d 0..31 / 32..63
    float mrun = -INFINITY, lrun = 0.f;

    // staging addresses (whole block covers one 64x64 tile per tensor)
    const int srow = tid >> 3, sgc = tid & 7;
    const int ssw = (sgc ^ (srow & 7)) * 8;
    const u16* Ksrc = Kb + (size_t)srow * 1024 + ssw;
    const u16* Vsrc = Vb + (size_t)srow * SD + ssw;

    gload16(Ksrc, &Kl[0][tid * 8]);
    gload16(Vsrc, &Vl[0][tid * 8]);
    __syncthreads();

    int cur = 0;
    for (int tt = 0; tt < 16; ++tt) {
        if (tt < 15) {
            const int t1 = (tt + 1) << 6;
            gload16(Ksrc + (size_t)t1 * 1024, &Kl[cur ^ 1][tid * 8]);
            gload16(Vsrc + t1, &Vl[cur ^ 1][tid * 8]);
        }
        // ---- QK^T: S^T[t][q], A = K rows, B = Q ----
        f32x16 st0 = {}, st1 = {};
        const u16* Kc = &Kl[cur][0];
#pragma unroll
        for (int ks = 0; ks < 4; ++ks) {
            const int g = (((ks * 2 + hi) ^ (lq & 7)) * 8);
            bf16x8 k0 = *reinterpret_cast<const bf16x8*>(Kc + lq * 64 + g);
            bf16x8 k1 = *reinterpret_cast<const bf16x8*>(Kc + (32 + lq) * 64 + g);
            st0 = __builtin_amdgcn_mfma_f32_32x32x16_bf16(k0, qf[ks], st0, 0, 0, 0);
            st1 = __builtin_amdgcn_mfma_f32_32x32x16_bf16(k1, qf[ks], st1, 0, 0, 0);
        }
        // ---- online softmax: lane owns q = lq; partner lane (^32) has the
        // complementary 32 t-values ----
        float mx = st0[0];
#pragma unroll
        for (int r = 1; r < 16; ++r) mx = fmaxf(mx, st0[r]);
#pragma unroll
        for (int r = 0; r < 16; ++r) mx = fmaxf(mx, st1[r]);
        mx = fmaxf(mx, __shfl_xor(mx, 32));
        const float mn = fmaxf(mrun, mx * 0.125f);
        const float al = __expf(mrun - mn);
        mrun = mn;
        float ps = 0.f;
        float p0[16], p1[16];
#pragma unroll
        for (int r = 0; r < 16; ++r) { p0[r] = __expf(st0[r] * 0.125f - mn); ps += p0[r]; }
#pragma unroll
        for (int r = 0; r < 16; ++r) { p1[r] = __expf(st1[r] * 0.125f - mn); ps += p1[r]; }
        ps += __shfl_xor(ps, 32);
        lrun = lrun * al + ps;
#pragma unroll
        for (int r = 0; r < 16; ++r) { of0[r] *= al; of1[r] *= al; }

        // ---- PV: O^T += V^T · P^T.  Frag k-position j <-> t chosen as
        // {ks*16+4hi+0..3, ks*16+8+4hi+0..3} on BOTH operands. ----
        const u16* Vc = &Vl[cur][0];
#pragma unroll
        for (int ks = 0; ks < 4; ++ks) {
            union { unsigned w[4]; bf16x8 v; } pf;
            const int rb = (ks & 1) * 8;
            if (ks < 2) {
                pf.w[0] = cvt_pk(p0[rb + 0], p0[rb + 1]);
                pf.w[1] = cvt_pk(p0[rb + 2], p0[rb + 3]);
                pf.w[2] = cvt_pk(p0[rb + 4], p0[rb + 5]);
                pf.w[3] = cvt_pk(p0[rb + 6], p0[rb + 7]);
            } else {
                pf.w[0] = cvt_pk(p1[rb + 0], p1[rb + 1]);
                pf.w[1] = cvt_pk(p1[rb + 2], p1[rb + 3]);
                pf.w[2] = cvt_pk(p1[rb + 4], p1[rb + 5]);
                pf.w[3] = cvt_pk(p1[rb + 6], p1[rb + 7]);
            }
            const int e0 = ((2 * ks) ^ (lq & 7)) * 8 + hi * 4;
            const int e1 = ((2 * ks + 1) ^ (lq & 7)) * 8 + hi * 4;
            union { bf16x4 h[2]; bf16x8 v; } vf0, vf1;
            vf0.h[0] = *reinterpret_cast<const bf16x4*>(Vc + lq * 64 + e0);
            vf0.h[1] = *reinterpret_cast<const bf16x4*>(Vc + lq * 64 + e1);
            vf1.h[0] = *reinterpret_cast<const bf16x4*>(Vc + (32 + lq) * 64 + e0);
            vf1.h[1] = *reinterpret_cast<const bf16x4*>(Vc + (32 + lq) * 64 + e1);
            of0 = __builtin_amdgcn_mfma_f32_32x32x16_bf16(vf0.v, pf.v, of0, 0, 0, 0);
            of1 = __builtin_amdgcn_mfma_f32_32x32x16_bf16(vf1.v, pf.v, of1, 0, 0, 0);
        }
        __syncthreads();
        cur ^= 1;
    }

    // ---- epilogue: O^T[d][q], lane col q = lq; rows d = (r&3)+8*(r>>2)+4hi ----
    const float inv = 1.0f / lrun;
    u16* op = ao + ((size_t)n * SD + q0 + wv * 32 + lq) * CD + hh * HD;
#pragma unroll
    for (int g = 0; g < 4; ++g) {
        u16x4 o0, o1;
#pragma unroll
        for (int e = 0; e < 4; ++e) {
            o0[e] = f2bf(of0[g * 4 + e] * inv);
            o1[e] = f2bf(of1[g * 4 + e] * inv);
        }
        const int d0 = g * 8 + hi * 4;
        *reinterpret_cast<u16x4*>(op + d0) = o0;
        *reinterpret_cast<u16x4*>(op + 32 + d0) = o1;
    }
}

// ---------------------------------------------------------------------------
extern "C" void kernel_launch(void* const* d_in, const int* in_sizes, int n_in,
                              void* d_out, int out_size, void* d_ws, size_t ws_size,
                              hipStream_t stream)
{
    const float* x      = (const float*)d_in[0];
    const float* norm_w = (const float*)d_in[1];
    const float* norm_b = (const float*)d_in[2];
    const float* qkv_w  = (const float*)d_in[3];
    const float* qkv_b  = (const float*)d_in[4];
    const float* proj_w = (const float*)d_in[5];
    const float* proj_b = (const float*)d_in[6];

    // ws (u16 elems): h | qk | vt | ao | wq | wp   (~86 MiB)
    u16* h   = (u16*)d_ws;                        // [16][1024][512]
    u16* qkb = h + (size_t)NB * SD * CD;          // [16][1024][1024]  (Q|K)
    u16* vtb = qkb + (size_t)NB * SD * 1024;      // [16][512][1024]   (V^T)
    u16* ao  = vtb + (size_t)NB * 512 * SD;       // [16][1024][512]
    u16* wq  = ao + (size_t)NB * SD * CD;         // [1536][512]
    u16* wp  = wq + (size_t)1536 * CD;            // [512][512]

    hipLaunchKernelGGL(cvt_kernel, dim3(768), dim3(256), 0, stream, qkv_w, wq, 1536 * CD);
    hipLaunchKernelGGL(cvt_kernel, dim3(256), dim3(256), 0, stream, proj_w, wp, CD * CD);
    hipLaunchKernelGGL(gn_kernel, dim3(NB * 32), dim3(256), 0, stream, x, norm_w, norm_b, h);
    hipLaunchKernelGGL(mfma_gemm, dim3(8, 12, NB), dim3(256), 0, stream,
                       wq, h, qkv_b, (const float*)nullptr, (void*)qkb, vtb, 1536, 0);
    hipLaunchKernelGGL(attn_mfma, dim3(SD / 256, NB * NH), dim3(512), 0, stream,
                       qkb, vtb, ao);
    hipLaunchKernelGGL(mfma_gemm, dim3(8, 4, NB), dim3(256), 0, stream,
                       wp, ao, proj_b, x, (void*)d_out, (u16*)nullptr, 512, 1);
}